// Round 2
// baseline (6314.951 us; speedup 1.0000x reference)
//
#include <hip/hip_runtime.h>
#include <stdint.h>
#include <math.h>

// Problem constants
#define NTOK 4096   // B*S
#define H    1024
#define NHEAD 16
#define HD   64
#define SEQ  2048
#define NE   8
#define DDIM 1024

// ---------------- helpers ----------------

__device__ __forceinline__ int dot4(int a, int b, int c) {
#if __has_builtin(__builtin_amdgcn_sdot4)
  return __builtin_amdgcn_sdot4(a, b, c, false);
#else
  c += (int)(int8_t)(a)       * (int)(int8_t)(b);
  c += (int)(int8_t)(a >> 8)  * (int)(int8_t)(b >> 8);
  c += (int)(int8_t)(a >> 16) * (int)(int8_t)(b >> 16);
  c += (int)(int8_t)(a >> 24) * (int)(int8_t)(b >> 24);
  return c;
#endif
}

// 256-thread block reduce (double). op=0 sum, op=1 max. tmp: __shared__ double[4]
__device__ __forceinline__ double bredd(double v, int op, double* tmp) {
#pragma unroll
  for (int o = 32; o; o >>= 1) {
    double w = __shfl_xor(v, o);
    v = op ? fmax(v, w) : v + w;
  }
  int wid = threadIdx.x >> 6;
  if ((threadIdx.x & 63) == 0) tmp[wid] = v;
  __syncthreads();
  double r = op ? fmax(fmax(tmp[0], tmp[1]), fmax(tmp[2], tmp[3]))
                : (tmp[0] + tmp[1] + tmp[2] + tmp[3]);
  __syncthreads();
  return r;
}

// quantize 4 doubles to packed int8 with double scale (round-half-even like jnp.round)
__device__ __forceinline__ int qpackd(double n0, double n1, double n2, double n3, double s) {
  int a = (int)fmin(fmax(rint(n0 * s), -128.0), 127.0);
  int b = (int)fmin(fmax(rint(n1 * s), -128.0), 127.0);
  int c = (int)fmin(fmax(rint(n2 * s), -128.0), 127.0);
  int d = (int)fmin(fmax(rint(n3 * s), -128.0), 127.0);
  return (a & 255) | ((b & 255) << 8) | ((c & 255) << 16) | ((d & 255) << 24);
}

// map flat tensor id (0..27, each 1M elems) -> source pointer
__device__ __forceinline__ const float* wsrc(int tensor,
    const float* qw_, const float* kw_, const float* vw_, const float* ow_,
    const float* gw_, const float* uw_, const float* dw_) {
  if (tensor < 4) return tensor == 0 ? qw_ : tensor == 1 ? kw_ : tensor == 2 ? vw_ : ow_;
  if (tensor < 12) return gw_ + ((long long)(tensor - 4) << 20);
  if (tensor < 20) return uw_ + ((long long)(tensor - 12) << 20);
  return dw_ + ((long long)(tensor - 20) << 20);
}

// ---------------- weight quantization (fp64 scale, deterministic) ----------------
// 28 tensors x 1M elements. Stage 1: per-block |w| sums (double). Stage 2: per-tensor
// deterministic reduce -> scale. Stage 3: ternary quantize with fp64 decisions.

__global__ __launch_bounds__(256) void k_absum(
    const float* qw_, const float* kw_, const float* vw_, const float* ow_,
    const float* gw_, const float* uw_, const float* dw_, double* partial) {
  __shared__ double tmp[4];
  int tensor = blockIdx.x >> 10;
  int j = ((blockIdx.x & 1023) << 10) + threadIdx.x * 4;
  const float* src = wsrc(tensor, qw_, kw_, vw_, ow_, gw_, uw_, dw_);
  float4 w = *(const float4*)(src + j);
  double v = fabs((double)w.x) + fabs((double)w.y) + fabs((double)w.z) + fabs((double)w.w);
  v = bredd(v, 0, tmp);
  if (threadIdx.x == 0) partial[blockIdx.x] = v;
}

__global__ __launch_bounds__(256) void k_wscale(const double* partial, double* wsd) {
  __shared__ double tmp[4];
  int tensor = blockIdx.x;
  const double* p = partial + (tensor << 10);
  int i = threadIdx.x * 4;
  double v = p[i] + p[i + 1] + p[i + 2] + p[i + 3];
  v = bredd(v, 0, tmp);
  if (threadIdx.x == 0) wsd[tensor] = 1.0 / fmax(v * (1.0 / 1048576.0), 1e-5);
}

__global__ __launch_bounds__(256) void k_quantw(
    const float* qw_, const float* kw_, const float* vw_, const float* ow_,
    const float* gw_, const float* uw_, const float* dw_,
    const double* wsd, int8_t* qw) {
  int tensor = blockIdx.x >> 10;
  int j = ((blockIdx.x & 1023) << 10) + threadIdx.x * 4;
  const float* src = wsrc(tensor, qw_, kw_, vw_, ow_, gw_, uw_, dw_);
  double s = wsd[tensor];
  float4 w = *(const float4*)(src + j);
  int a = (int)fmin(fmax(rint((double)w.x * s), -1.0), 1.0);
  int b = (int)fmin(fmax(rint((double)w.y * s), -1.0), 1.0);
  int c = (int)fmin(fmax(rint((double)w.z * s), -1.0), 1.0);
  int d = (int)fmin(fmax(rint((double)w.w * s), -1.0), 1.0);
  ((int*)qw)[(tensor << 18) + (j >> 2)] =
      (a & 255) | ((b & 255) << 8) | ((c & 255) << 16) | ((d & 255) << 24);
}

// ---------------- rmsnorm + act_quant (attention input), fp64 decisions ----------------

__global__ __launch_bounds__(256) void k_rms1(const float* X, const float* lnw,
                                              int8_t* xq, double* xsd) {
  __shared__ double tmp[4];
  int t = blockIdx.x, tid = threadIdx.x;
  float4 xv = ((const float4*)(X + (long long)t * H))[tid];
  double x0 = xv.x, x1 = xv.y, x2 = xv.z, x3 = xv.w;
  double ss = x0 * x0 + x1 * x1 + x2 * x2 + x3 * x3;
  ss = bredd(ss, 0, tmp);
  double r = 1.0 / sqrt(ss * (1.0 / 1024.0) + 1e-5);
  float4 wv = ((const float4*)lnw)[tid];
  double n0 = x0 * r * wv.x, n1 = x1 * r * wv.y, n2 = x2 * r * wv.z, n3 = x3 * r * wv.w;
  double ma = fmax(fmax(fabs(n0), fabs(n1)), fmax(fabs(n2), fabs(n3)));
  ma = bredd(ma, 1, tmp);
  double s = 127.0 / fmax(ma, 1e-5);
  ((int*)xq)[t * 256 + tid] = qpackd(n0, n1, n2, n3, s);
  if (tid == 0) xsd[t] = s;
}

// act_quant only (rows of 1024 floats), fp64 decisions
__global__ __launch_bounds__(256) void k_actq(const float* X, int8_t* xq, double* xsd) {
  __shared__ double tmp[4];
  int t = blockIdx.x, tid = threadIdx.x;
  float4 xv = ((const float4*)(X + (long long)t * H))[tid];
  double x0 = xv.x, x1 = xv.y, x2 = xv.z, x3 = xv.w;
  double ma = fmax(fmax(fabs(x0), fabs(x1)), fmax(fabs(x2), fabs(x3)));
  ma = bredd(ma, 1, tmp);
  double s = 127.0 / fmax(ma, 1e-5);
  ((int*)xq)[t * 256 + tid] = qpackd(x0, x1, x2, x3, s);
  if (tid == 0) xsd[t] = s;
}

// ---------------- int8 GEMM: out[t,n] = res[t,n] + acc / (xs[t]*sw) ----------------
// T=4096, N=1024, K=1024. 64x64 tile per block, 4x4 per thread, TK=128 bytes.

__global__ __launch_bounds__(256) void k_gemm(
    const int8_t* __restrict__ Xq, const double* __restrict__ xsd,
    const int8_t* __restrict__ W, const double* __restrict__ wsd, int widx,
    const float* __restrict__ residual, float* __restrict__ out) {
  __shared__ int Xs[64][33];
  __shared__ int Wt[64][33];
  int tid = threadIdx.x;
  int t0 = blockIdx.y * 64, n0 = blockIdx.x * 64;
  const int* Xg = (const int*)Xq;
  const int* Wg = (const int*)W;
  int acc[4][4] = {};
  int lr = tid >> 5, lc = tid & 31;
  int ty = tid >> 4, tx = tid & 15;
  for (int k0 = 0; k0 < 1024; k0 += 128) {
    int kc = k0 >> 2;
#pragma unroll
    for (int i = 0; i < 8; i++) {
      int rr = lr + i * 8;
      Xs[rr][lc] = Xg[(t0 + rr) * 256 + kc + lc];
      Wt[rr][lc] = Wg[(n0 + rr) * 256 + kc + lc];
    }
    __syncthreads();
#pragma unroll
    for (int kk = 0; kk < 32; kk++) {
      int a0 = Xs[ty * 4 + 0][kk], a1 = Xs[ty * 4 + 1][kk];
      int a2 = Xs[ty * 4 + 2][kk], a3 = Xs[ty * 4 + 3][kk];
      int b0 = Wt[tx * 4 + 0][kk], b1 = Wt[tx * 4 + 1][kk];
      int b2 = Wt[tx * 4 + 2][kk], b3 = Wt[tx * 4 + 3][kk];
      acc[0][0] = dot4(a0, b0, acc[0][0]); acc[0][1] = dot4(a0, b1, acc[0][1]);
      acc[0][2] = dot4(a0, b2, acc[0][2]); acc[0][3] = dot4(a0, b3, acc[0][3]);
      acc[1][0] = dot4(a1, b0, acc[1][0]); acc[1][1] = dot4(a1, b1, acc[1][1]);
      acc[1][2] = dot4(a1, b2, acc[1][2]); acc[1][3] = dot4(a1, b3, acc[1][3]);
      acc[2][0] = dot4(a2, b0, acc[2][0]); acc[2][1] = dot4(a2, b1, acc[2][1]);
      acc[2][2] = dot4(a2, b2, acc[2][2]); acc[2][3] = dot4(a2, b3, acc[2][3]);
      acc[3][0] = dot4(a3, b0, acc[3][0]); acc[3][1] = dot4(a3, b1, acc[3][1]);
      acc[3][2] = dot4(a3, b2, acc[3][2]); acc[3][3] = dot4(a3, b3, acc[3][3]);
    }
    __syncthreads();
  }
  double sw = wsd[widx];
#pragma unroll
  for (int i = 0; i < 4; i++) {
    int t = t0 + ty * 4 + i;
    double inv = 1.0 / (xsd[t] * sw);
#pragma unroll
    for (int j = 0; j < 4; j++) {
      int n = n0 + tx * 4 + j;
      double v = (double)acc[i][j] * inv;
      if (residual) v += (double)residual[(long long)t * H + n];
      out[(long long)t * H + n] = (float)v;
    }
  }
}

// ---------------- attention: wave-per-query online softmax (fp32, precise exp) ----------------

__global__ __launch_bounds__(256) void k_attn(float* __restrict__ QO,
                                              const float* __restrict__ K,
                                              const float* __restrict__ V) {
  int wid = threadIdx.x >> 6, lane = threadIdx.x & 63;
  int row = blockIdx.x * 4 + wid;            // b*32768 + head*2048 + sq
  int sq = row & (SEQ - 1);
  int head = (row >> 11) & (NHEAD - 1);
  int b = row >> 15;
  long long base = (long long)b * SEQ * H + head * HD + lane;
  float qv = QO[base + (long long)sq * H] * 0.125f;  // 1/sqrt(64)
  float m = -INFINITY, l = 0.f, acc = 0.f;
  for (int j = 0; j <= sq; j++) {
    float kv = K[base + (long long)j * H];
    float p = qv * kv;
#pragma unroll
    for (int o = 32; o; o >>= 1) p += __shfl_xor(p, o);
    float mn = fmaxf(m, p);
    float al = expf(m - mn);
    float w = expf(p - mn);
    float vv = V[base + (long long)j * H];
    l = l * al + w;
    acc = acc * al + w * vv;
    m = mn;
  }
  QO[base + (long long)sq * H] = acc / l;
}

// ---------------- rmsnorm2 + router (argmax, fp64) + act_quant ----------------

__global__ __launch_bounds__(256) void k_rms2_router(
    const float* X2, const float* lnw, const float* rw,
    int8_t* xq, double* xsd, int* eidx) {
  __shared__ double tmp[4];
  __shared__ double xn[1024];
  __shared__ double logits[8];
  int t = blockIdx.x, tid = threadIdx.x;
  float4 xv = ((const float4*)(X2 + (long long)t * H))[tid];
  double x0 = xv.x, x1 = xv.y, x2 = xv.z, x3 = xv.w;
  double ss = x0 * x0 + x1 * x1 + x2 * x2 + x3 * x3;
  ss = bredd(ss, 0, tmp);
  double r = 1.0 / sqrt(ss * (1.0 / 1024.0) + 1e-5);
  float4 wv = ((const float4*)lnw)[tid];
  double n0 = x0 * r * wv.x, n1 = x1 * r * wv.y, n2 = x2 * r * wv.z, n3 = x3 * r * wv.w;
  xn[tid * 4 + 0] = n0; xn[tid * 4 + 1] = n1;
  xn[tid * 4 + 2] = n2; xn[tid * 4 + 3] = n3;
  double ma = fmax(fmax(fabs(n0), fabs(n1)), fmax(fabs(n2), fabs(n3)));
  ma = bredd(ma, 1, tmp);  // contains syncthreads -> xn visible
  double s = 127.0 / fmax(ma, 1e-5);
  ((int*)xq)[t * 256 + tid] = qpackd(n0, n1, n2, n3, s);
  if (tid == 0) xsd[t] = s;
  // router: wave 0, 8 lanes per expert, fp64 logits
  if (tid < 64) {
    int e = tid >> 3, i = tid & 7;
    const float* wr = rw + e * 1024;
    double p = 0.0;
    for (int h = i; h < 1024; h += 8) p += xn[h] * (double)wr[h];
    p += __shfl_xor(p, 1);
    p += __shfl_xor(p, 2);
    p += __shfl_xor(p, 4);
    if (i == 0) logits[e] = p;
  }
  __syncthreads();
  if (tid == 0) {
    double best = logits[0];
    int bi = 0;
    for (int e = 1; e < 8; e++)
      if (logits[e] > best) { best = logits[e]; bi = e; }
    eidx[t] = bi;
  }
}

// ---------------- MoE gate/up: hh[t,d] = relu(g)^2 * u for selected expert ----------------

__global__ __launch_bounds__(256) void k_moe_gu(
    const int8_t* __restrict__ xq, const double* __restrict__ xsd,
    const int* __restrict__ eidx, const int8_t* __restrict__ qw,
    const double* __restrict__ wsd, float* __restrict__ hh) {
  __shared__ int xrow[256];
  int t = blockIdx.x, tid = threadIdx.x;
  xrow[tid] = ((const int*)(xq + (long long)t * H))[tid];
  __syncthreads();
  int e = eidx[t];
  double st = xsd[t];
  double inv_g = 1.0 / (st * wsd[4 + e]);
  double inv_u = 1.0 / (st * wsd[12 + e]);
  const int* gbase = (const int*)qw + ((long long)(4 + e) << 18);
  const int* ubase = (const int*)qw + ((long long)(12 + e) << 18);
  int wid = tid >> 6, lane = tid & 63;
  for (int d = wid; d < DDIM; d += 4) {
    const int* gr = gbase + d * 256;
    const int* ur = ubase + d * 256;
    int ag = 0, au = 0;
#pragma unroll
    for (int c = 0; c < 4; c++) {
      int xc = xrow[lane + c * 64];
      ag = dot4(gr[lane + c * 64], xc, ag);
      au = dot4(ur[lane + c * 64], xc, au);
    }
#pragma unroll
    for (int o = 32; o; o >>= 1) {
      ag += __shfl_xor(ag, o);
      au += __shfl_xor(au, o);
    }
    if (lane == 0) {
      double g = (double)ag * inv_g, u = (double)au * inv_u;
      double rg = fmax(g, 0.0);
      hh[(long long)t * DDIM + d] = (float)(rg * rg * u);
    }
  }
}

// ---------------- MoE down + residual -> final output ----------------

__global__ __launch_bounds__(256) void k_moe_down(
    const int8_t* __restrict__ hq, const double* __restrict__ hsd,
    const int* __restrict__ eidx, const int8_t* __restrict__ qw,
    const double* __restrict__ wsd, const float* __restrict__ x2,
    float* __restrict__ out) {
  __shared__ int xrow[256];
  int t = blockIdx.x, tid = threadIdx.x;
  xrow[tid] = ((const int*)(hq + (long long)t * DDIM))[tid];
  __syncthreads();
  int e = eidx[t];
  double inv = 1.0 / (hsd[t] * wsd[20 + e]);
  const int* dbase = (const int*)qw + ((long long)(20 + e) << 18);
  int wid = tid >> 6, lane = tid & 63;
  for (int h = wid; h < H; h += 4) {
    const int* dr = dbase + h * 256;
    int a = 0;
#pragma unroll
    for (int c = 0; c < 4; c++) a = dot4(dr[lane + c * 64], xrow[lane + c * 64], a);
#pragma unroll
    for (int o = 32; o; o >>= 1) a += __shfl_xor(a, o);
    if (lane == 0)
      out[(long long)t * H + h] = (float)((double)x2[(long long)t * H + h] + (double)a * inv);
  }
}

// ---------------- launch ----------------
// ws layout (bytes):
//   0        partial double[28*1024]  (224 KB)
//   229376   wsd double[28]
//   229600   xsd double[4096] (32 KB)
//   262368   eidx int[4096]
//   1MB      qw int8: 28 x 1MB (q,k,v,o, gate[8], up[8], down[8])
//   32MB     qbuf fp32 16MB (q -> attn out in place)
//   48MB     kbuf fp32 16MB (k -> moe hh)
//   64MB     vbuf fp32 16MB (v -> x2 residual)
//   80MB     xq int8 4MB  (act_quant buffer, reused 4x)
// total 84MB

extern "C" void kernel_launch(void* const* d_in, const int* in_sizes, int n_in,
                              void* d_out, int out_size, void* d_ws, size_t ws_size,
                              hipStream_t stream) {
  const float* x   = (const float*)d_in[0];
  const float* qw_ = (const float*)d_in[1];
  const float* kw_ = (const float*)d_in[2];
  const float* vw_ = (const float*)d_in[3];
  const float* ow_ = (const float*)d_in[4];
  const float* ln1 = (const float*)d_in[5];
  const float* ln2 = (const float*)d_in[6];
  const float* rw  = (const float*)d_in[7];
  const float* gw  = (const float*)d_in[8];
  const float* uw  = (const float*)d_in[9];
  const float* dw  = (const float*)d_in[10];
  float* out = (float*)d_out;

  uint8_t* ws = (uint8_t*)d_ws;
  double* partial = (double*)ws;
  double* wsd   = (double*)(ws + 229376);
  double* xsd   = (double*)(ws + 229600);
  int*    eidx  = (int*)(ws + 262368);
  int8_t* qw    = (int8_t*)(ws + (1ull << 20));
  float*  qbuf  = (float*)(ws + (32ull << 20));
  float*  kbuf  = (float*)(ws + (48ull << 20));
  float*  vbuf  = (float*)(ws + (64ull << 20));
  int8_t* xq    = (int8_t*)(ws + (80ull << 20));

  // weight quantization (deterministic fp64 scales)
  k_absum<<<28 * 1024, 256, 0, stream>>>(qw_, kw_, vw_, ow_, gw, uw, dw, partial);
  k_wscale<<<28, 256, 0, stream>>>(partial, wsd);
  k_quantw<<<28 * 1024, 256, 0, stream>>>(qw_, kw_, vw_, ow_, gw, uw, dw, wsd, qw);

  // attention input: rmsnorm + act_quant
  k_rms1<<<NTOK, 256, 0, stream>>>(x, ln1, xq, xsd);
  // q/k/v projections (exact int8 x ternary GEMM)
  k_gemm<<<dim3(16, 64), 256, 0, stream>>>(xq, xsd, qw,             wsd, 0, nullptr, qbuf);
  k_gemm<<<dim3(16, 64), 256, 0, stream>>>(xq, xsd, qw + (1 << 20), wsd, 1, nullptr, kbuf);
  k_gemm<<<dim3(16, 64), 256, 0, stream>>>(xq, xsd, qw + (2 << 20), wsd, 2, nullptr, vbuf);
  // causal attention, h written in place over qbuf
  k_attn<<<NTOK * NHEAD / 4, 256, 0, stream>>>(qbuf, kbuf, vbuf);
  // o projection with residual: x2 = x + bitlinear(h, o_w) -> vbuf
  k_actq<<<NTOK, 256, 0, stream>>>(qbuf, xq, xsd);
  k_gemm<<<dim3(16, 64), 256, 0, stream>>>(xq, xsd, qw + (3 << 20), wsd, 3, x, vbuf);
  // MoE: rmsnorm2 + router argmax + act_quant
  k_rms2_router<<<NTOK, 256, 0, stream>>>(vbuf, ln2, rw, xq, xsd, eidx);
  k_moe_gu<<<NTOK, 256, 0, stream>>>(xq, xsd, eidx, qw, wsd, kbuf);
  k_actq<<<NTOK, 256, 0, stream>>>(kbuf, xq, xsd);
  k_moe_down<<<NTOK, 256, 0, stream>>>(xq, xsd, eidx, qw, wsd, vbuf, out);
}

// Round 3
// 2648.196 us; speedup vs baseline: 2.3846x; 2.3846x over previous
//
#include <hip/hip_runtime.h>
#include <stdint.h>
#include <math.h>

// Problem constants
#define NTOK 4096   // B*S
#define H    1024
#define NHEAD 16
#define HD   64
#define SEQ  2048
#define NE   8
#define DDIM 1024

// ---------------- helpers ----------------

__device__ __forceinline__ int dot4(int a, int b, int c) {
#if __has_builtin(__builtin_amdgcn_sdot4)
  return __builtin_amdgcn_sdot4(a, b, c, false);
#else
  c += (int)(int8_t)(a)       * (int)(int8_t)(b);
  c += (int)(int8_t)(a >> 8)  * (int)(int8_t)(b >> 8);
  c += (int)(int8_t)(a >> 16) * (int)(int8_t)(b >> 16);
  c += (int)(int8_t)(a >> 24) * (int)(int8_t)(b >> 24);
  return c;
#endif
}

// 256-thread block reduce (double). op=0 sum, op=1 max. tmp: __shared__ double[4]
__device__ __forceinline__ double bredd(double v, int op, double* tmp) {
#pragma unroll
  for (int o = 32; o; o >>= 1) {
    double w = __shfl_xor(v, o);
    v = op ? fmax(v, w) : v + w;
  }
  int wid = threadIdx.x >> 6;
  if ((threadIdx.x & 63) == 0) tmp[wid] = v;
  __syncthreads();
  double r = op ? fmax(fmax(tmp[0], tmp[1]), fmax(tmp[2], tmp[3]))
                : (tmp[0] + tmp[1] + tmp[2] + tmp[3]);
  __syncthreads();
  return r;
}

// quantize 4 doubles to packed int8 with double scale (round-half-even like jnp.round)
__device__ __forceinline__ int qpackd(double n0, double n1, double n2, double n3, double s) {
  int a = (int)fmin(fmax(rint(n0 * s), -128.0), 127.0);
  int b = (int)fmin(fmax(rint(n1 * s), -128.0), 127.0);
  int c = (int)fmin(fmax(rint(n2 * s), -128.0), 127.0);
  int d = (int)fmin(fmax(rint(n3 * s), -128.0), 127.0);
  return (a & 255) | ((b & 255) << 8) | ((c & 255) << 16) | ((d & 255) << 24);
}

// map flat tensor id (0..27, each 1M elems) -> source pointer
__device__ __forceinline__ const float* wsrc(int tensor,
    const float* qw_, const float* kw_, const float* vw_, const float* ow_,
    const float* gw_, const float* uw_, const float* dw_) {
  if (tensor < 4) return tensor == 0 ? qw_ : tensor == 1 ? kw_ : tensor == 2 ? vw_ : ow_;
  if (tensor < 12) return gw_ + ((long long)(tensor - 4) << 20);
  if (tensor < 20) return uw_ + ((long long)(tensor - 12) << 20);
  return dw_ + ((long long)(tensor - 20) << 20);
}

// ---------------- weight quantization (fp64 scale, deterministic) ----------------

__global__ __launch_bounds__(256) void k_absum(
    const float* qw_, const float* kw_, const float* vw_, const float* ow_,
    const float* gw_, const float* uw_, const float* dw_, double* partial) {
  __shared__ double tmp[4];
  int tensor = blockIdx.x >> 10;
  int j = ((blockIdx.x & 1023) << 10) + threadIdx.x * 4;
  const float* src = wsrc(tensor, qw_, kw_, vw_, ow_, gw_, uw_, dw_);
  float4 w = *(const float4*)(src + j);
  double v = fabs((double)w.x) + fabs((double)w.y) + fabs((double)w.z) + fabs((double)w.w);
  v = bredd(v, 0, tmp);
  if (threadIdx.x == 0) partial[blockIdx.x] = v;
}

__global__ __launch_bounds__(256) void k_wscale(const double* partial, double* wsd) {
  __shared__ double tmp[4];
  int tensor = blockIdx.x;
  const double* p = partial + (tensor << 10);
  int i = threadIdx.x * 4;
  double v = p[i] + p[i + 1] + p[i + 2] + p[i + 3];
  v = bredd(v, 0, tmp);
  if (threadIdx.x == 0) wsd[tensor] = 1.0 / fmax(v * (1.0 / 1048576.0), 1e-5);
}

__global__ __launch_bounds__(256) void k_quantw(
    const float* qw_, const float* kw_, const float* vw_, const float* ow_,
    const float* gw_, const float* uw_, const float* dw_,
    const double* wsd, int8_t* qw) {
  int tensor = blockIdx.x >> 10;
  int j = ((blockIdx.x & 1023) << 10) + threadIdx.x * 4;
  const float* src = wsrc(tensor, qw_, kw_, vw_, ow_, gw_, uw_, dw_);
  double s = wsd[tensor];
  float4 w = *(const float4*)(src + j);
  int a = (int)fmin(fmax(rint((double)w.x * s), -1.0), 1.0);
  int b = (int)fmin(fmax(rint((double)w.y * s), -1.0), 1.0);
  int c = (int)fmin(fmax(rint((double)w.z * s), -1.0), 1.0);
  int d = (int)fmin(fmax(rint((double)w.w * s), -1.0), 1.0);
  ((int*)qw)[(tensor << 18) + (j >> 2)] =
      (a & 255) | ((b & 255) << 8) | ((c & 255) << 16) | ((d & 255) << 24);
}

// ---------------- rmsnorm + act_quant (attention input), fp64 decisions ----------------

__global__ __launch_bounds__(256) void k_rms1(const float* X, const float* lnw,
                                              int8_t* xq, double* xsd) {
  __shared__ double tmp[4];
  int t = blockIdx.x, tid = threadIdx.x;
  float4 xv = ((const float4*)(X + (long long)t * H))[tid];
  double x0 = xv.x, x1 = xv.y, x2 = xv.z, x3 = xv.w;
  double ss = x0 * x0 + x1 * x1 + x2 * x2 + x3 * x3;
  ss = bredd(ss, 0, tmp);
  double r = 1.0 / sqrt(ss * (1.0 / 1024.0) + 1e-5);
  float4 wv = ((const float4*)lnw)[tid];
  double n0 = x0 * r * wv.x, n1 = x1 * r * wv.y, n2 = x2 * r * wv.z, n3 = x3 * r * wv.w;
  double ma = fmax(fmax(fabs(n0), fabs(n1)), fmax(fabs(n2), fabs(n3)));
  ma = bredd(ma, 1, tmp);
  double s = 127.0 / fmax(ma, 1e-5);
  ((int*)xq)[t * 256 + tid] = qpackd(n0, n1, n2, n3, s);
  if (tid == 0) xsd[t] = s;
}

// act_quant only (rows of 1024 floats), fp64 decisions
__global__ __launch_bounds__(256) void k_actq(const float* X, int8_t* xq, double* xsd) {
  __shared__ double tmp[4];
  int t = blockIdx.x, tid = threadIdx.x;
  float4 xv = ((const float4*)(X + (long long)t * H))[tid];
  double x0 = xv.x, x1 = xv.y, x2 = xv.z, x3 = xv.w;
  double ma = fmax(fmax(fabs(x0), fabs(x1)), fmax(fabs(x2), fabs(x3)));
  ma = bredd(ma, 1, tmp);
  double s = 127.0 / fmax(ma, 1e-5);
  ((int*)xq)[t * 256 + tid] = qpackd(x0, x1, x2, x3, s);
  if (tid == 0) xsd[t] = s;
}

// ---------------- int8 GEMM: out[t,n] = res[t,n] + acc / (xs[t]*sw) ----------------

__global__ __launch_bounds__(256) void k_gemm(
    const int8_t* __restrict__ Xq, const double* __restrict__ xsd,
    const int8_t* __restrict__ W, const double* __restrict__ wsd, int widx,
    const float* __restrict__ residual, float* __restrict__ out) {
  __shared__ int Xs[64][33];
  __shared__ int Wt[64][33];
  int tid = threadIdx.x;
  int t0 = blockIdx.y * 64, n0 = blockIdx.x * 64;
  const int* Xg = (const int*)Xq;
  const int* Wg = (const int*)W;
  int acc[4][4] = {};
  int lr = tid >> 5, lc = tid & 31;
  int ty = tid >> 4, tx = tid & 15;
  for (int k0 = 0; k0 < 1024; k0 += 128) {
    int kc = k0 >> 2;
#pragma unroll
    for (int i = 0; i < 8; i++) {
      int rr = lr + i * 8;
      Xs[rr][lc] = Xg[(t0 + rr) * 256 + kc + lc];
      Wt[rr][lc] = Wg[(n0 + rr) * 256 + kc + lc];
    }
    __syncthreads();
#pragma unroll
    for (int kk = 0; kk < 32; kk++) {
      int a0 = Xs[ty * 4 + 0][kk], a1 = Xs[ty * 4 + 1][kk];
      int a2 = Xs[ty * 4 + 2][kk], a3 = Xs[ty * 4 + 3][kk];
      int b0 = Wt[tx * 4 + 0][kk], b1 = Wt[tx * 4 + 1][kk];
      int b2 = Wt[tx * 4 + 2][kk], b3 = Wt[tx * 4 + 3][kk];
      acc[0][0] = dot4(a0, b0, acc[0][0]); acc[0][1] = dot4(a0, b1, acc[0][1]);
      acc[0][2] = dot4(a0, b2, acc[0][2]); acc[0][3] = dot4(a0, b3, acc[0][3]);
      acc[1][0] = dot4(a1, b0, acc[1][0]); acc[1][1] = dot4(a1, b1, acc[1][1]);
      acc[1][2] = dot4(a1, b2, acc[1][2]); acc[1][3] = dot4(a1, b3, acc[1][3]);
      acc[2][0] = dot4(a2, b0, acc[2][0]); acc[2][1] = dot4(a2, b1, acc[2][1]);
      acc[2][2] = dot4(a2, b2, acc[2][2]); acc[2][3] = dot4(a2, b3, acc[2][3]);
      acc[3][0] = dot4(a3, b0, acc[3][0]); acc[3][1] = dot4(a3, b1, acc[3][1]);
      acc[3][2] = dot4(a3, b2, acc[3][2]); acc[3][3] = dot4(a3, b3, acc[3][3]);
    }
    __syncthreads();
  }
  double sw = wsd[widx];
#pragma unroll
  for (int i = 0; i < 4; i++) {
    int t = t0 + ty * 4 + i;
    double inv = 1.0 / (xsd[t] * sw);
#pragma unroll
    for (int j = 0; j < 4; j++) {
      int n = n0 + tx * 4 + j;
      double v = (double)acc[i][j] * inv;
      if (residual) v += (double)residual[(long long)t * H + n];
      out[(long long)t * H + n] = (float)v;
    }
  }
}

// ---------------- attention: flash-tiled, lane-per-query ----------------
// grid (8 qgroups, 16 heads, 2 batch), block 256 = 4 waves.
// Wave w covers queries qlo + w*64 .. +63, one query per lane: q row (64f) and
// O accumulator (64f) live in VGPRs. K/V staged in LDS 64-key tiles; per key,
// broadcast-read K/V rows. Online softmax per lane; O-rescale is skipped unless
// __any lane records a new max (uniform branch, ~14% of steps).

__global__ __launch_bounds__(256, 1) void k_attn(float* __restrict__ QO,
                                                 const float* __restrict__ K,
                                                 const float* __restrict__ V) {
  __shared__ float Ks[64][68];   // +4 pad: stagger staging-store banks
  __shared__ float Vs[64][68];
  int g = blockIdx.x, head = blockIdx.y, b = blockIdx.z;
  int tid = threadIdx.x;
  int wv = tid >> 6, lane = tid & 63;
  int qlo = g * 256;
  int sq = qlo + wv * 64 + lane;
  long long rowbase = ((long long)(b * SEQ + sq)) * H + head * HD;

  float4 qreg[16];
  const float4* qp = (const float4*)(QO + rowbase);
#pragma unroll
  for (int i = 0; i < 16; i++) {
    float4 t = qp[i];
    qreg[i] = make_float4(t.x * 0.125f, t.y * 0.125f, t.z * 0.125f, t.w * 0.125f);
  }
  float acc[64];
#pragma unroll
  for (int i = 0; i < 64; i++) acc[i] = 0.f;
  float m = -INFINITY, l = 0.f;

  int nk = qlo + 256;              // keys needed by this block
  int swq = qlo + wv * 64 + 63;    // wave's last query
  int skey = tid >> 2;             // staging: key row 0..63
  int sdc = (tid & 3) << 4;        // staging: d chunk 0/16/32/48

  for (int ko = 0; ko < nk; ko += 64) {
    long long srow = ((long long)(b * SEQ + ko + skey)) * H + head * HD + sdc;
    const float4* kg = (const float4*)(K + srow);
    const float4* vg = (const float4*)(V + srow);
    float4* ksd = (float4*)&Ks[skey][sdc];
    float4* vsd = (float4*)&Vs[skey][sdc];
#pragma unroll
    for (int i = 0; i < 4; i++) ksd[i] = kg[i];
#pragma unroll
    for (int i = 0; i < 4; i++) vsd[i] = vg[i];
    __syncthreads();

    if (ko <= swq) {
      int kmax = (swq - ko + 1 < 64) ? (swq - ko + 1) : 64;
      for (int kk = 0; kk < kmax; kk++) {
        const float4* kr = (const float4*)&Ks[kk][0];
        float p0 = 0.f, p1 = 0.f, p2 = 0.f, p3 = 0.f;
#pragma unroll
        for (int i = 0; i < 16; i++) {
          float4 kv = kr[i];
          p0 = fmaf(qreg[i].x, kv.x, p0);
          p1 = fmaf(qreg[i].y, kv.y, p1);
          p2 = fmaf(qreg[i].z, kv.z, p2);
          p3 = fmaf(qreg[i].w, kv.w, p3);
        }
        float p = (p0 + p1) + (p2 + p3);
        if (ko + kk > sq) p = -INFINITY;   // causal mask (per lane)
        bool nm = (p > m);
        float mn = nm ? p : m;
        float w = __expf(p - mn);
        const float4* vr = (const float4*)&Vs[kk][0];
        if (__any(nm)) {
          float al = __expf(m - mn);       // lanes w/o new max: exp(0)=1
          l = fmaf(l, al, w);
#pragma unroll
          for (int i = 0; i < 16; i++) {
            float4 vvv = vr[i];
            acc[4*i+0] = fmaf(acc[4*i+0], al, w * vvv.x);
            acc[4*i+1] = fmaf(acc[4*i+1], al, w * vvv.y);
            acc[4*i+2] = fmaf(acc[4*i+2], al, w * vvv.z);
            acc[4*i+3] = fmaf(acc[4*i+3], al, w * vvv.w);
          }
        } else {
          l += w;
#pragma unroll
          for (int i = 0; i < 16; i++) {
            float4 vvv = vr[i];
            acc[4*i+0] = fmaf(w, vvv.x, acc[4*i+0]);
            acc[4*i+1] = fmaf(w, vvv.y, acc[4*i+1]);
            acc[4*i+2] = fmaf(w, vvv.z, acc[4*i+2]);
            acc[4*i+3] = fmaf(w, vvv.w, acc[4*i+3]);
          }
        }
        m = mn;
      }
    }
    __syncthreads();
  }

  float invl = 1.f / l;
  float4* outp = (float4*)(QO + rowbase);
#pragma unroll
  for (int i = 0; i < 16; i++)
    outp[i] = make_float4(acc[4*i] * invl, acc[4*i+1] * invl,
                          acc[4*i+2] * invl, acc[4*i+3] * invl);
}

// ---------------- rmsnorm2 + router (argmax, fp64) + act_quant ----------------

__global__ __launch_bounds__(256) void k_rms2_router(
    const float* X2, const float* lnw, const float* rw,
    int8_t* xq, double* xsd, int* eidx) {
  __shared__ double tmp[4];
  __shared__ double xn[1024];
  __shared__ double logits[8];
  int t = blockIdx.x, tid = threadIdx.x;
  float4 xv = ((const float4*)(X2 + (long long)t * H))[tid];
  double x0 = xv.x, x1 = xv.y, x2 = xv.z, x3 = xv.w;
  double ss = x0 * x0 + x1 * x1 + x2 * x2 + x3 * x3;
  ss = bredd(ss, 0, tmp);
  double r = 1.0 / sqrt(ss * (1.0 / 1024.0) + 1e-5);
  float4 wv = ((const float4*)lnw)[tid];
  double n0 = x0 * r * wv.x, n1 = x1 * r * wv.y, n2 = x2 * r * wv.z, n3 = x3 * r * wv.w;
  xn[tid * 4 + 0] = n0; xn[tid * 4 + 1] = n1;
  xn[tid * 4 + 2] = n2; xn[tid * 4 + 3] = n3;
  double ma = fmax(fmax(fabs(n0), fabs(n1)), fmax(fabs(n2), fabs(n3)));
  ma = bredd(ma, 1, tmp);  // contains syncthreads -> xn visible
  double s = 127.0 / fmax(ma, 1e-5);
  ((int*)xq)[t * 256 + tid] = qpackd(n0, n1, n2, n3, s);
  if (tid == 0) xsd[t] = s;
  if (tid < 64) {
    int e = tid >> 3, i = tid & 7;
    const float* wr = rw + e * 1024;
    double p = 0.0;
    for (int h = i; h < 1024; h += 8) p += xn[h] * (double)wr[h];
    p += __shfl_xor(p, 1);
    p += __shfl_xor(p, 2);
    p += __shfl_xor(p, 4);
    if (i == 0) logits[e] = p;
  }
  __syncthreads();
  if (tid == 0) {
    double best = logits[0];
    int bi = 0;
    for (int e = 1; e < 8; e++)
      if (logits[e] > best) { best = logits[e]; bi = e; }
    eidx[t] = bi;
  }
}

// ---------------- MoE gate/up: hh[t,d] = relu(g)^2 * u for selected expert ----------------

__global__ __launch_bounds__(256) void k_moe_gu(
    const int8_t* __restrict__ xq, const double* __restrict__ xsd,
    const int* __restrict__ eidx, const int8_t* __restrict__ qw,
    const double* __restrict__ wsd, float* __restrict__ hh) {
  __shared__ int xrow[256];
  int t = blockIdx.x, tid = threadIdx.x;
  xrow[tid] = ((const int*)(xq + (long long)t * H))[tid];
  __syncthreads();
  int e = eidx[t];
  double st = xsd[t];
  double inv_g = 1.0 / (st * wsd[4 + e]);
  double inv_u = 1.0 / (st * wsd[12 + e]);
  const int* gbase = (const int*)qw + ((long long)(4 + e) << 18);
  const int* ubase = (const int*)qw + ((long long)(12 + e) << 18);
  int wid = tid >> 6, lane = tid & 63;
  for (int d = wid; d < DDIM; d += 4) {
    const int* gr = gbase + d * 256;
    const int* ur = ubase + d * 256;
    int ag = 0, au = 0;
#pragma unroll
    for (int c = 0; c < 4; c++) {
      int xc = xrow[lane + c * 64];
      ag = dot4(gr[lane + c * 64], xc, ag);
      au = dot4(ur[lane + c * 64], xc, au);
    }
#pragma unroll
    for (int o = 32; o; o >>= 1) {
      ag += __shfl_xor(ag, o);
      au += __shfl_xor(au, o);
    }
    if (lane == 0) {
      double g = (double)ag * inv_g, u = (double)au * inv_u;
      double rg = fmax(g, 0.0);
      hh[(long long)t * DDIM + d] = (float)(rg * rg * u);
    }
  }
}

// ---------------- MoE down + residual -> final output ----------------

__global__ __launch_bounds__(256) void k_moe_down(
    const int8_t* __restrict__ hq, const double* __restrict__ hsd,
    const int* __restrict__ eidx, const int8_t* __restrict__ qw,
    const double* __restrict__ wsd, const float* __restrict__ x2,
    float* __restrict__ out) {
  __shared__ int xrow[256];
  int t = blockIdx.x, tid = threadIdx.x;
  xrow[tid] = ((const int*)(hq + (long long)t * DDIM))[tid];
  __syncthreads();
  int e = eidx[t];
  double inv = 1.0 / (hsd[t] * wsd[20 + e]);
  const int* dbase = (const int*)qw + ((long long)(20 + e) << 18);
  int wid = tid >> 6, lane = tid & 63;
  for (int h = wid; h < H; h += 4) {
    const int* dr = dbase + h * 256;
    int a = 0;
#pragma unroll
    for (int c = 0; c < 4; c++) a = dot4(dr[lane + c * 64], xrow[lane + c * 64], a);
#pragma unroll
    for (int o = 32; o; o >>= 1) a += __shfl_xor(a, o);
    if (lane == 0)
      out[(long long)t * H + h] = (float)((double)x2[(long long)t * H + h] + (double)a * inv);
  }
}

// ---------------- launch ----------------
// ws layout (bytes):
//   0        partial double[28*1024]  (224 KB)
//   229376   wsd double[28]
//   229600   xsd double[4096] (32 KB)
//   262368   eidx int[4096]
//   1MB      qw int8: 28 x 1MB (q,k,v,o, gate[8], up[8], down[8])
//   32MB     qbuf fp32 16MB (q -> attn out in place)
//   48MB     kbuf fp32 16MB (k -> moe hh)
//   64MB     vbuf fp32 16MB (v -> x2 residual)
//   80MB     xq int8 4MB  (act_quant buffer, reused 4x)

extern "C" void kernel_launch(void* const* d_in, const int* in_sizes, int n_in,
                              void* d_out, int out_size, void* d_ws, size_t ws_size,
                              hipStream_t stream) {
  const float* x   = (const float*)d_in[0];
  const float* qw_ = (const float*)d_in[1];
  const float* kw_ = (const float*)d_in[2];
  const float* vw_ = (const float*)d_in[3];
  const float* ow_ = (const float*)d_in[4];
  const float* ln1 = (const float*)d_in[5];
  const float* ln2 = (const float*)d_in[6];
  const float* rw  = (const float*)d_in[7];
  const float* gw  = (const float*)d_in[8];
  const float* uw  = (const float*)d_in[9];
  const float* dw  = (const float*)d_in[10];
  float* out = (float*)d_out;

  uint8_t* ws = (uint8_t*)d_ws;
  double* partial = (double*)ws;
  double* wsd   = (double*)(ws + 229376);
  double* xsd   = (double*)(ws + 229600);
  int*    eidx  = (int*)(ws + 262368);
  int8_t* qw    = (int8_t*)(ws + (1ull << 20));
  float*  qbuf  = (float*)(ws + (32ull << 20));
  float*  kbuf  = (float*)(ws + (48ull << 20));
  float*  vbuf  = (float*)(ws + (64ull << 20));
  int8_t* xq    = (int8_t*)(ws + (80ull << 20));

  // weight quantization (deterministic fp64 scales)
  k_absum<<<28 * 1024, 256, 0, stream>>>(qw_, kw_, vw_, ow_, gw, uw, dw, partial);
  k_wscale<<<28, 256, 0, stream>>>(partial, wsd);
  k_quantw<<<28 * 1024, 256, 0, stream>>>(qw_, kw_, vw_, ow_, gw, uw, dw, wsd, qw);

  // attention input: rmsnorm + act_quant
  k_rms1<<<NTOK, 256, 0, stream>>>(x, ln1, xq, xsd);
  // q/k/v projections (exact int8 x ternary GEMM)
  k_gemm<<<dim3(16, 64), 256, 0, stream>>>(xq, xsd, qw,             wsd, 0, nullptr, qbuf);
  k_gemm<<<dim3(16, 64), 256, 0, stream>>>(xq, xsd, qw + (1 << 20), wsd, 1, nullptr, kbuf);
  k_gemm<<<dim3(16, 64), 256, 0, stream>>>(xq, xsd, qw + (2 << 20), wsd, 2, nullptr, vbuf);
  // causal flash attention, h written in place over qbuf
  k_attn<<<dim3(8, NHEAD, 2), 256, 0, stream>>>(qbuf, kbuf, vbuf);
  // o projection with residual: x2 = x + bitlinear(h, o_w) -> vbuf
  k_actq<<<NTOK, 256, 0, stream>>>(qbuf, xq, xsd);
  k_gemm<<<dim3(16, 64), 256, 0, stream>>>(xq, xsd, qw + (3 << 20), wsd, 3, x, vbuf);
  // MoE: rmsnorm2 + router argmax + act_quant
  k_rms2_router<<<NTOK, 256, 0, stream>>>(vbuf, ln2, rw, xq, xsd, eidx);
  k_moe_gu<<<NTOK, 256, 0, stream>>>(xq, xsd, eidx, qw, wsd, kbuf);
  k_actq<<<NTOK, 256, 0, stream>>>(kbuf, xq, xsd);
  k_moe_down<<<NTOK, 256, 0, stream>>>(xq, xsd, eidx, qw, wsd, vbuf, out);
}

// Round 4
// 2238.448 us; speedup vs baseline: 2.8211x; 1.1830x over previous
//
#include <hip/hip_runtime.h>
#include <stdint.h>
#include <math.h>

// Problem constants
#define NTOK 4096   // B*S
#define H    1024
#define NHEAD 16
#define HD   64
#define SEQ  2048
#define NE   8
#define DDIM 1024

// ---------------- helpers ----------------

__device__ __forceinline__ int dot4(int a, int b, int c) {
#if __has_builtin(__builtin_amdgcn_sdot4)
  return __builtin_amdgcn_sdot4(a, b, c, false);
#else
  c += (int)(int8_t)(a)       * (int)(int8_t)(b);
  c += (int)(int8_t)(a >> 8)  * (int)(int8_t)(b >> 8);
  c += (int)(int8_t)(a >> 16) * (int)(int8_t)(b >> 16);
  c += (int)(int8_t)(a >> 24) * (int)(int8_t)(b >> 24);
  return c;
#endif
}

// 256-thread block reduce (double). op=0 sum, op=1 max. tmp: __shared__ double[4]
__device__ __forceinline__ double bredd(double v, int op, double* tmp) {
#pragma unroll
  for (int o = 32; o; o >>= 1) {
    double w = __shfl_xor(v, o);
    v = op ? fmax(v, w) : v + w;
  }
  int wid = threadIdx.x >> 6;
  if ((threadIdx.x & 63) == 0) tmp[wid] = v;
  __syncthreads();
  double r = op ? fmax(fmax(tmp[0], tmp[1]), fmax(tmp[2], tmp[3]))
                : (tmp[0] + tmp[1] + tmp[2] + tmp[3]);
  __syncthreads();
  return r;
}

// quantize 4 doubles to packed int8 with double scale (round-half-even like jnp.round)
__device__ __forceinline__ int qpackd(double n0, double n1, double n2, double n3, double s) {
  int a = (int)fmin(fmax(rint(n0 * s), -128.0), 127.0);
  int b = (int)fmin(fmax(rint(n1 * s), -128.0), 127.0);
  int c = (int)fmin(fmax(rint(n2 * s), -128.0), 127.0);
  int d = (int)fmin(fmax(rint(n3 * s), -128.0), 127.0);
  return (a & 255) | ((b & 255) << 8) | ((c & 255) << 16) | ((d & 255) << 24);
}

// map flat tensor id (0..27, each 1M elems) -> source pointer
__device__ __forceinline__ const float* wsrc(int tensor,
    const float* qw_, const float* kw_, const float* vw_, const float* ow_,
    const float* gw_, const float* uw_, const float* dw_) {
  if (tensor < 4) return tensor == 0 ? qw_ : tensor == 1 ? kw_ : tensor == 2 ? vw_ : ow_;
  if (tensor < 12) return gw_ + ((long long)(tensor - 4) << 20);
  if (tensor < 20) return uw_ + ((long long)(tensor - 12) << 20);
  return dw_ + ((long long)(tensor - 20) << 20);
}

// ---------------- weight quantization (fp64 scale, deterministic) ----------------

__global__ __launch_bounds__(256) void k_absum(
    const float* qw_, const float* kw_, const float* vw_, const float* ow_,
    const float* gw_, const float* uw_, const float* dw_, double* partial) {
  __shared__ double tmp[4];
  int tensor = blockIdx.x >> 10;
  int j = ((blockIdx.x & 1023) << 10) + threadIdx.x * 4;
  const float* src = wsrc(tensor, qw_, kw_, vw_, ow_, gw_, uw_, dw_);
  float4 w = *(const float4*)(src + j);
  double v = fabs((double)w.x) + fabs((double)w.y) + fabs((double)w.z) + fabs((double)w.w);
  v = bredd(v, 0, tmp);
  if (threadIdx.x == 0) partial[blockIdx.x] = v;
}

__global__ __launch_bounds__(256) void k_wscale(const double* partial, double* wsd) {
  __shared__ double tmp[4];
  int tensor = blockIdx.x;
  const double* p = partial + (tensor << 10);
  int i = threadIdx.x * 4;
  double v = p[i] + p[i + 1] + p[i + 2] + p[i + 3];
  v = bredd(v, 0, tmp);
  if (threadIdx.x == 0) wsd[tensor] = 1.0 / fmax(v * (1.0 / 1048576.0), 1e-5);
}

__global__ __launch_bounds__(256) void k_quantw(
    const float* qw_, const float* kw_, const float* vw_, const float* ow_,
    const float* gw_, const float* uw_, const float* dw_,
    const double* wsd, int8_t* qw) {
  int tensor = blockIdx.x >> 10;
  int j = ((blockIdx.x & 1023) << 10) + threadIdx.x * 4;
  const float* src = wsrc(tensor, qw_, kw_, vw_, ow_, gw_, uw_, dw_);
  double s = wsd[tensor];
  float4 w = *(const float4*)(src + j);
  int a = (int)fmin(fmax(rint((double)w.x * s), -1.0), 1.0);
  int b = (int)fmin(fmax(rint((double)w.y * s), -1.0), 1.0);
  int c = (int)fmin(fmax(rint((double)w.z * s), -1.0), 1.0);
  int d = (int)fmin(fmax(rint((double)w.w * s), -1.0), 1.0);
  ((int*)qw)[(tensor << 18) + (j >> 2)] =
      (a & 255) | ((b & 255) << 8) | ((c & 255) << 16) | ((d & 255) << 24);
}

// ---------------- rmsnorm + act_quant (attention input), fp64 decisions ----------------

__global__ __launch_bounds__(256) void k_rms1(const float* X, const float* lnw,
                                              int8_t* xq, double* xsd) {
  __shared__ double tmp[4];
  int t = blockIdx.x, tid = threadIdx.x;
  float4 xv = ((const float4*)(X + (long long)t * H))[tid];
  double x0 = xv.x, x1 = xv.y, x2 = xv.z, x3 = xv.w;
  double ss = x0 * x0 + x1 * x1 + x2 * x2 + x3 * x3;
  ss = bredd(ss, 0, tmp);
  double r = 1.0 / sqrt(ss * (1.0 / 1024.0) + 1e-5);
  float4 wv = ((const float4*)lnw)[tid];
  double n0 = x0 * r * wv.x, n1 = x1 * r * wv.y, n2 = x2 * r * wv.z, n3 = x3 * r * wv.w;
  double ma = fmax(fmax(fabs(n0), fabs(n1)), fmax(fabs(n2), fabs(n3)));
  ma = bredd(ma, 1, tmp);
  double s = 127.0 / fmax(ma, 1e-5);
  ((int*)xq)[t * 256 + tid] = qpackd(n0, n1, n2, n3, s);
  if (tid == 0) xsd[t] = s;
}

// act_quant only (rows of 1024 floats), fp64 decisions
__global__ __launch_bounds__(256) void k_actq(const float* X, int8_t* xq, double* xsd) {
  __shared__ double tmp[4];
  int t = blockIdx.x, tid = threadIdx.x;
  float4 xv = ((const float4*)(X + (long long)t * H))[tid];
  double x0 = xv.x, x1 = xv.y, x2 = xv.z, x3 = xv.w;
  double ma = fmax(fmax(fabs(x0), fabs(x1)), fmax(fabs(x2), fabs(x3)));
  ma = bredd(ma, 1, tmp);
  double s = 127.0 / fmax(ma, 1e-5);
  ((int*)xq)[t * 256 + tid] = qpackd(x0, x1, x2, x3, s);
  if (tid == 0) xsd[t] = s;
}

// ---------------- int8 GEMM: out[t,n] = res[t,n] + acc / (xs[t]*sw) ----------------

__global__ __launch_bounds__(256) void k_gemm(
    const int8_t* __restrict__ Xq, const double* __restrict__ xsd,
    const int8_t* __restrict__ W, const double* __restrict__ wsd, int widx,
    const float* __restrict__ residual, float* __restrict__ out) {
  __shared__ int Xs[64][33];
  __shared__ int Wt[64][33];
  int tid = threadIdx.x;
  int t0 = blockIdx.y * 64, n0 = blockIdx.x * 64;
  const int* Xg = (const int*)Xq;
  const int* Wg = (const int*)W;
  int acc[4][4] = {};
  int lr = tid >> 5, lc = tid & 31;
  int ty = tid >> 4, tx = tid & 15;
  for (int k0 = 0; k0 < 1024; k0 += 128) {
    int kc = k0 >> 2;
#pragma unroll
    for (int i = 0; i < 8; i++) {
      int rr = lr + i * 8;
      Xs[rr][lc] = Xg[(t0 + rr) * 256 + kc + lc];
      Wt[rr][lc] = Wg[(n0 + rr) * 256 + kc + lc];
    }
    __syncthreads();
#pragma unroll
    for (int kk = 0; kk < 32; kk++) {
      int a0 = Xs[ty * 4 + 0][kk], a1 = Xs[ty * 4 + 1][kk];
      int a2 = Xs[ty * 4 + 2][kk], a3 = Xs[ty * 4 + 3][kk];
      int b0 = Wt[tx * 4 + 0][kk], b1 = Wt[tx * 4 + 1][kk];
      int b2 = Wt[tx * 4 + 2][kk], b3 = Wt[tx * 4 + 3][kk];
      acc[0][0] = dot4(a0, b0, acc[0][0]); acc[0][1] = dot4(a0, b1, acc[0][1]);
      acc[0][2] = dot4(a0, b2, acc[0][2]); acc[0][3] = dot4(a0, b3, acc[0][3]);
      acc[1][0] = dot4(a1, b0, acc[1][0]); acc[1][1] = dot4(a1, b1, acc[1][1]);
      acc[1][2] = dot4(a1, b2, acc[1][2]); acc[1][3] = dot4(a1, b3, acc[1][3]);
      acc[2][0] = dot4(a2, b0, acc[2][0]); acc[2][1] = dot4(a2, b1, acc[2][1]);
      acc[2][2] = dot4(a2, b2, acc[2][2]); acc[2][3] = dot4(a2, b3, acc[2][3]);
      acc[3][0] = dot4(a3, b0, acc[3][0]); acc[3][1] = dot4(a3, b1, acc[3][1]);
      acc[3][2] = dot4(a3, b2, acc[3][2]); acc[3][3] = dot4(a3, b3, acc[3][3]);
    }
    __syncthreads();
  }
  double sw = wsd[widx];
#pragma unroll
  for (int i = 0; i < 4; i++) {
    int t = t0 + ty * 4 + i;
    double inv = 1.0 / (xsd[t] * sw);
#pragma unroll
    for (int j = 0; j < 4; j++) {
      int n = n0 + tx * 4 + j;
      double v = (double)acc[i][j] * inv;
      if (residual) v += (double)residual[(long long)t * H + n];
      out[(long long)t * H + n] = (float)v;
    }
  }
}

// ---------------- attention: flash-tiled, 4-lanes-per-query ----------------
// grid (32 qgroups, 16 heads, 2 batch), block 256 = 4 waves, 64 queries/block.
// Wave = 16 queries; lane = q*4 + dpart, each lane owns d in [dpart*16, +16).
// 4096 waves total -> 4 waves/SIMD (vs 1 before) so LDS latency is hidden and
// the LDS pipe can run at throughput. Per key-step/wave: 8 ds_read_b128
// (4 distinct addrs 64B apart -> 2-way bank alias = free), 32 FMA, quad-shuffle
// p-reduce. Online softmax duplicated over the 4 lanes of a query (consistent).

__global__ __launch_bounds__(256) void k_attn(float* __restrict__ QO,
                                              const float* __restrict__ K,
                                              const float* __restrict__ V) {
  __shared__ float Ks[64][68];   // +4 pad
  __shared__ float Vs[64][68];
  int g = blockIdx.x, head = blockIdx.y, b = blockIdx.z;
  int tid = threadIdx.x;
  int wv = tid >> 6, lane = tid & 63;
  int qi = lane >> 2, dpart = lane & 3;
  int qlo = g * 64;
  int sq = qlo + wv * 16 + qi;
  int d0 = dpart << 4;
  long long rowbase = ((long long)(b * SEQ + sq)) * H + head * HD + d0;

  float4 qreg[4];
  const float4* qp = (const float4*)(QO + rowbase);
#pragma unroll
  for (int i = 0; i < 4; i++) {
    float4 t = qp[i];
    qreg[i] = make_float4(t.x * 0.125f, t.y * 0.125f, t.z * 0.125f, t.w * 0.125f);
  }
  float acc[16];
#pragma unroll
  for (int i = 0; i < 16; i++) acc[i] = 0.f;
  float m = -INFINITY, l = 0.f;

  int nk = qlo + 64;               // keys needed by this block
  int swq = qlo + wv * 16 + 15;    // wave's last query
  int skey = tid >> 2;             // staging: key row 0..63
  int sdc = (tid & 3) << 4;        // staging: d chunk 0/16/32/48

  for (int ko = 0; ko < nk; ko += 64) {
    long long srow = ((long long)(b * SEQ + ko + skey)) * H + head * HD + sdc;
    const float4* kg = (const float4*)(K + srow);
    const float4* vg = (const float4*)(V + srow);
    float4* ksd = (float4*)&Ks[skey][sdc];
    float4* vsd = (float4*)&Vs[skey][sdc];
#pragma unroll
    for (int i = 0; i < 4; i++) ksd[i] = kg[i];
#pragma unroll
    for (int i = 0; i < 4; i++) vsd[i] = vg[i];
    __syncthreads();

    if (ko <= swq) {
      int kmax = (swq - ko + 1 < 64) ? (swq - ko + 1) : 64;
      for (int kk = 0; kk < kmax; kk++) {
        const float4* kr = (const float4*)&Ks[kk][d0];
        float p0 = 0.f, p1 = 0.f, p2 = 0.f, p3 = 0.f;
#pragma unroll
        for (int i = 0; i < 4; i++) {
          float4 kv = kr[i];
          p0 = fmaf(qreg[i].x, kv.x, p0);
          p1 = fmaf(qreg[i].y, kv.y, p1);
          p2 = fmaf(qreg[i].z, kv.z, p2);
          p3 = fmaf(qreg[i].w, kv.w, p3);
        }
        float p = (p0 + p1) + (p2 + p3);
        p += __shfl_xor(p, 1);          // quad butterfly: full 64-dim dot
        p += __shfl_xor(p, 2);
        if (ko + kk > sq) p = -INFINITY;   // causal mask (per query)
        bool nm = (p > m);
        float mn = nm ? p : m;
        float w = __expf(p - mn);
        const float4* vr = (const float4*)&Vs[kk][d0];
        if (__any(nm)) {
          float al = __expf(m - mn);       // lanes w/o new max: exp(0)=1
          l = fmaf(l, al, w);
#pragma unroll
          for (int i = 0; i < 4; i++) {
            float4 vvv = vr[i];
            acc[4*i+0] = fmaf(acc[4*i+0], al, w * vvv.x);
            acc[4*i+1] = fmaf(acc[4*i+1], al, w * vvv.y);
            acc[4*i+2] = fmaf(acc[4*i+2], al, w * vvv.z);
            acc[4*i+3] = fmaf(acc[4*i+3], al, w * vvv.w);
          }
        } else {
          l += w;
#pragma unroll
          for (int i = 0; i < 4; i++) {
            float4 vvv = vr[i];
            acc[4*i+0] = fmaf(w, vvv.x, acc[4*i+0]);
            acc[4*i+1] = fmaf(w, vvv.y, acc[4*i+1]);
            acc[4*i+2] = fmaf(w, vvv.z, acc[4*i+2]);
            acc[4*i+3] = fmaf(w, vvv.w, acc[4*i+3]);
          }
        }
        m = mn;
      }
    }
    __syncthreads();
  }

  float invl = 1.f / l;
  float4* outp = (float4*)(QO + rowbase);
#pragma unroll
  for (int i = 0; i < 4; i++)
    outp[i] = make_float4(acc[4*i] * invl, acc[4*i+1] * invl,
                          acc[4*i+2] * invl, acc[4*i+3] * invl);
}

// ---------------- rmsnorm2 + router (argmax, fp64) + act_quant ----------------

__global__ __launch_bounds__(256) void k_rms2_router(
    const float* X2, const float* lnw, const float* rw,
    int8_t* xq, double* xsd, int* eidx) {
  __shared__ double tmp[4];
  __shared__ double xn[1024];
  __shared__ double logits[8];
  int t = blockIdx.x, tid = threadIdx.x;
  float4 xv = ((const float4*)(X2 + (long long)t * H))[tid];
  double x0 = xv.x, x1 = xv.y, x2 = xv.z, x3 = xv.w;
  double ss = x0 * x0 + x1 * x1 + x2 * x2 + x3 * x3;
  ss = bredd(ss, 0, tmp);
  double r = 1.0 / sqrt(ss * (1.0 / 1024.0) + 1e-5);
  float4 wv = ((const float4*)lnw)[tid];
  double n0 = x0 * r * wv.x, n1 = x1 * r * wv.y, n2 = x2 * r * wv.z, n3 = x3 * r * wv.w;
  xn[tid * 4 + 0] = n0; xn[tid * 4 + 1] = n1;
  xn[tid * 4 + 2] = n2; xn[tid * 4 + 3] = n3;
  double ma = fmax(fmax(fabs(n0), fabs(n1)), fmax(fabs(n2), fabs(n3)));
  ma = bredd(ma, 1, tmp);  // contains syncthreads -> xn visible
  double s = 127.0 / fmax(ma, 1e-5);
  ((int*)xq)[t * 256 + tid] = qpackd(n0, n1, n2, n3, s);
  if (tid == 0) xsd[t] = s;
  if (tid < 64) {
    int e = tid >> 3, i = tid & 7;
    const float* wr = rw + e * 1024;
    double p = 0.0;
    for (int h = i; h < 1024; h += 8) p += xn[h] * (double)wr[h];
    p += __shfl_xor(p, 1);
    p += __shfl_xor(p, 2);
    p += __shfl_xor(p, 4);
    if (i == 0) logits[e] = p;
  }
  __syncthreads();
  if (tid == 0) {
    double best = logits[0];
    int bi = 0;
    for (int e = 1; e < 8; e++)
      if (logits[e] > best) { best = logits[e]; bi = e; }
    eidx[t] = bi;
  }
}

// ---------------- MoE gate/up: hh[t,d] = relu(g)^2 * u for selected expert ----------------

__global__ __launch_bounds__(256) void k_moe_gu(
    const int8_t* __restrict__ xq, const double* __restrict__ xsd,
    const int* __restrict__ eidx, const int8_t* __restrict__ qw,
    const double* __restrict__ wsd, float* __restrict__ hh) {
  __shared__ int xrow[256];
  int t = blockIdx.x, tid = threadIdx.x;
  xrow[tid] = ((const int*)(xq + (long long)t * H))[tid];
  __syncthreads();
  int e = eidx[t];
  double st = xsd[t];
  double inv_g = 1.0 / (st * wsd[4 + e]);
  double inv_u = 1.0 / (st * wsd[12 + e]);
  const int* gbase = (const int*)qw + ((long long)(4 + e) << 18);
  const int* ubase = (const int*)qw + ((long long)(12 + e) << 18);
  int wid = tid >> 6, lane = tid & 63;
  for (int d = wid; d < DDIM; d += 4) {
    const int* gr = gbase + d * 256;
    const int* ur = ubase + d * 256;
    int ag = 0, au = 0;
#pragma unroll
    for (int c = 0; c < 4; c++) {
      int xc = xrow[lane + c * 64];
      ag = dot4(gr[lane + c * 64], xc, ag);
      au = dot4(ur[lane + c * 64], xc, au);
    }
#pragma unroll
    for (int o = 32; o; o >>= 1) {
      ag += __shfl_xor(ag, o);
      au += __shfl_xor(au, o);
    }
    if (lane == 0) {
      double g = (double)ag * inv_g, u = (double)au * inv_u;
      double rg = fmax(g, 0.0);
      hh[(long long)t * DDIM + d] = (float)(rg * rg * u);
    }
  }
}

// ---------------- MoE down + residual -> final output ----------------

__global__ __launch_bounds__(256) void k_moe_down(
    const int8_t* __restrict__ hq, const double* __restrict__ hsd,
    const int* __restrict__ eidx, const int8_t* __restrict__ qw,
    const double* __restrict__ wsd, const float* __restrict__ x2,
    float* __restrict__ out) {
  __shared__ int xrow[256];
  int t = blockIdx.x, tid = threadIdx.x;
  xrow[tid] = ((const int*)(hq + (long long)t * DDIM))[tid];
  __syncthreads();
  int e = eidx[t];
  double inv = 1.0 / (hsd[t] * wsd[20 + e]);
  const int* dbase = (const int*)qw + ((long long)(20 + e) << 18);
  int wid = tid >> 6, lane = tid & 63;
  for (int h = wid; h < H; h += 4) {
    const int* dr = dbase + h * 256;
    int a = 0;
#pragma unroll
    for (int c = 0; c < 4; c++) a = dot4(dr[lane + c * 64], xrow[lane + c * 64], a);
#pragma unroll
    for (int o = 32; o; o >>= 1) a += __shfl_xor(a, o);
    if (lane == 0)
      out[(long long)t * H + h] = (float)((double)x2[(long long)t * H + h] + (double)a * inv);
  }
}

// ---------------- launch ----------------
// ws layout (bytes):
//   0        partial double[28*1024]  (224 KB)
//   229376   wsd double[28]
//   229600   xsd double[4096] (32 KB)
//   262368   eidx int[4096]
//   1MB      qw int8: 28 x 1MB (q,k,v,o, gate[8], up[8], down[8])
//   32MB     qbuf fp32 16MB (q -> attn out in place)
//   48MB     kbuf fp32 16MB (k -> moe hh)
//   64MB     vbuf fp32 16MB (v -> x2 residual)
//   80MB     xq int8 4MB  (act_quant buffer, reused 4x)

extern "C" void kernel_launch(void* const* d_in, const int* in_sizes, int n_in,
                              void* d_out, int out_size, void* d_ws, size_t ws_size,
                              hipStream_t stream) {
  const float* x   = (const float*)d_in[0];
  const float* qw_ = (const float*)d_in[1];
  const float* kw_ = (const float*)d_in[2];
  const float* vw_ = (const float*)d_in[3];
  const float* ow_ = (const float*)d_in[4];
  const float* ln1 = (const float*)d_in[5];
  const float* ln2 = (const float*)d_in[6];
  const float* rw  = (const float*)d_in[7];
  const float* gw  = (const float*)d_in[8];
  const float* uw  = (const float*)d_in[9];
  const float* dw  = (const float*)d_in[10];
  float* out = (float*)d_out;

  uint8_t* ws = (uint8_t*)d_ws;
  double* partial = (double*)ws;
  double* wsd   = (double*)(ws + 229376);
  double* xsd   = (double*)(ws + 229600);
  int*    eidx  = (int*)(ws + 262368);
  int8_t* qw    = (int8_t*)(ws + (1ull << 20));
  float*  qbuf  = (float*)(ws + (32ull << 20));
  float*  kbuf  = (float*)(ws + (48ull << 20));
  float*  vbuf  = (float*)(ws + (64ull << 20));
  int8_t* xq    = (int8_t*)(ws + (80ull << 20));

  // weight quantization (deterministic fp64 scales)
  k_absum<<<28 * 1024, 256, 0, stream>>>(qw_, kw_, vw_, ow_, gw, uw, dw, partial);
  k_wscale<<<28, 256, 0, stream>>>(partial, wsd);
  k_quantw<<<28 * 1024, 256, 0, stream>>>(qw_, kw_, vw_, ow_, gw, uw, dw, wsd, qw);

  // attention input: rmsnorm + act_quant
  k_rms1<<<NTOK, 256, 0, stream>>>(x, ln1, xq, xsd);
  // q/k/v projections (exact int8 x ternary GEMM)
  k_gemm<<<dim3(16, 64), 256, 0, stream>>>(xq, xsd, qw,             wsd, 0, nullptr, qbuf);
  k_gemm<<<dim3(16, 64), 256, 0, stream>>>(xq, xsd, qw + (1 << 20), wsd, 1, nullptr, kbuf);
  k_gemm<<<dim3(16, 64), 256, 0, stream>>>(xq, xsd, qw + (2 << 20), wsd, 2, nullptr, vbuf);
  // causal flash attention, h written in place over qbuf
  k_attn<<<dim3(32, NHEAD, 2), 256, 0, stream>>>(qbuf, kbuf, vbuf);
  // o projection with residual: x2 = x + bitlinear(h, o_w) -> vbuf
  k_actq<<<NTOK, 256, 0, stream>>>(qbuf, xq, xsd);
  k_gemm<<<dim3(16, 64), 256, 0, stream>>>(xq, xsd, qw + (3 << 20), wsd, 3, x, vbuf);
  // MoE: rmsnorm2 + router argmax + act_quant
  k_rms2_router<<<NTOK, 256, 0, stream>>>(vbuf, ln2, rw, xq, xsd, eidx);
  k_moe_gu<<<NTOK, 256, 0, stream>>>(xq, xsd, eidx, qw, wsd, kbuf);
  k_actq<<<NTOK, 256, 0, stream>>>(kbuf, xq, xsd);
  k_moe_down<<<NTOK, 256, 0, stream>>>(xq, xsd, eidx, qw, wsd, vbuf, out);
}

// Round 5
// 2196.350 us; speedup vs baseline: 2.8752x; 1.0192x over previous
//
#include <hip/hip_runtime.h>
#include <stdint.h>
#include <math.h>

// Problem constants
#define NTOK 4096   // B*S
#define H    1024
#define NHEAD 16
#define HD   64
#define SEQ  2048
#define NE   8
#define DDIM 1024

// ---------------- helpers ----------------

__device__ __forceinline__ int dot4(int a, int b, int c) {
#if __has_builtin(__builtin_amdgcn_sdot4)
  return __builtin_amdgcn_sdot4(a, b, c, false);
#else
  c += (int)(int8_t)(a)       * (int)(int8_t)(b);
  c += (int)(int8_t)(a >> 8)  * (int)(int8_t)(b >> 8);
  c += (int)(int8_t)(a >> 16) * (int)(int8_t)(b >> 16);
  c += (int)(int8_t)(a >> 24) * (int)(int8_t)(b >> 24);
  return c;
#endif
}

// 256-thread block reduce (double). op=0 sum, op=1 max. tmp: __shared__ double[4]
__device__ __forceinline__ double bredd(double v, int op, double* tmp) {
#pragma unroll
  for (int o = 32; o; o >>= 1) {
    double w = __shfl_xor(v, o);
    v = op ? fmax(v, w) : v + w;
  }
  int wid = threadIdx.x >> 6;
  if ((threadIdx.x & 63) == 0) tmp[wid] = v;
  __syncthreads();
  double r = op ? fmax(fmax(tmp[0], tmp[1]), fmax(tmp[2], tmp[3]))
                : (tmp[0] + tmp[1] + tmp[2] + tmp[3]);
  __syncthreads();
  return r;
}

// quantize 4 doubles to packed int8 with double scale (round-half-even like jnp.round)
__device__ __forceinline__ int qpackd(double n0, double n1, double n2, double n3, double s) {
  int a = (int)fmin(fmax(rint(n0 * s), -128.0), 127.0);
  int b = (int)fmin(fmax(rint(n1 * s), -128.0), 127.0);
  int c = (int)fmin(fmax(rint(n2 * s), -128.0), 127.0);
  int d = (int)fmin(fmax(rint(n3 * s), -128.0), 127.0);
  return (a & 255) | ((b & 255) << 8) | ((c & 255) << 16) | ((d & 255) << 24);
}

// map flat tensor id (0..27, each 1M elems) -> source pointer
__device__ __forceinline__ const float* wsrc(int tensor,
    const float* qw_, const float* kw_, const float* vw_, const float* ow_,
    const float* gw_, const float* uw_, const float* dw_) {
  if (tensor < 4) return tensor == 0 ? qw_ : tensor == 1 ? kw_ : tensor == 2 ? vw_ : ow_;
  if (tensor < 12) return gw_ + ((long long)(tensor - 4) << 20);
  if (tensor < 20) return uw_ + ((long long)(tensor - 12) << 20);
  return dw_ + ((long long)(tensor - 20) << 20);
}

// ---------------- weight quantization (fp64 scale, deterministic) ----------------

__global__ __launch_bounds__(256) void k_absum(
    const float* qw_, const float* kw_, const float* vw_, const float* ow_,
    const float* gw_, const float* uw_, const float* dw_, double* partial) {
  __shared__ double tmp[4];
  int tensor = blockIdx.x >> 10;
  int j = ((blockIdx.x & 1023) << 10) + threadIdx.x * 4;
  const float* src = wsrc(tensor, qw_, kw_, vw_, ow_, gw_, uw_, dw_);
  float4 w = *(const float4*)(src + j);
  double v = fabs((double)w.x) + fabs((double)w.y) + fabs((double)w.z) + fabs((double)w.w);
  v = bredd(v, 0, tmp);
  if (threadIdx.x == 0) partial[blockIdx.x] = v;
}

__global__ __launch_bounds__(256) void k_wscale(const double* partial, double* wsd) {
  __shared__ double tmp[4];
  int tensor = blockIdx.x;
  const double* p = partial + (tensor << 10);
  int i = threadIdx.x * 4;
  double v = p[i] + p[i + 1] + p[i + 2] + p[i + 3];
  v = bredd(v, 0, tmp);
  if (threadIdx.x == 0) wsd[tensor] = 1.0 / fmax(v * (1.0 / 1048576.0), 1e-5);
}

__global__ __launch_bounds__(256) void k_quantw(
    const float* qw_, const float* kw_, const float* vw_, const float* ow_,
    const float* gw_, const float* uw_, const float* dw_,
    const double* wsd, int8_t* qw) {
  int tensor = blockIdx.x >> 10;
  int j = ((blockIdx.x & 1023) << 10) + threadIdx.x * 4;
  const float* src = wsrc(tensor, qw_, kw_, vw_, ow_, gw_, uw_, dw_);
  double s = wsd[tensor];
  float4 w = *(const float4*)(src + j);
  int a = (int)fmin(fmax(rint((double)w.x * s), -1.0), 1.0);
  int b = (int)fmin(fmax(rint((double)w.y * s), -1.0), 1.0);
  int c = (int)fmin(fmax(rint((double)w.z * s), -1.0), 1.0);
  int d = (int)fmin(fmax(rint((double)w.w * s), -1.0), 1.0);
  ((int*)qw)[(tensor << 18) + (j >> 2)] =
      (a & 255) | ((b & 255) << 8) | ((c & 255) << 16) | ((d & 255) << 24);
}

// ---------------- rmsnorm + act_quant (attention input), fp64 decisions ----------------

__global__ __launch_bounds__(256) void k_rms1(const float* X, const float* lnw,
                                              int8_t* xq, double* xsd) {
  __shared__ double tmp[4];
  int t = blockIdx.x, tid = threadIdx.x;
  float4 xv = ((const float4*)(X + (long long)t * H))[tid];
  double x0 = xv.x, x1 = xv.y, x2 = xv.z, x3 = xv.w;
  double ss = x0 * x0 + x1 * x1 + x2 * x2 + x3 * x3;
  ss = bredd(ss, 0, tmp);
  double r = 1.0 / sqrt(ss * (1.0 / 1024.0) + 1e-5);
  float4 wv = ((const float4*)lnw)[tid];
  double n0 = x0 * r * wv.x, n1 = x1 * r * wv.y, n2 = x2 * r * wv.z, n3 = x3 * r * wv.w;
  double ma = fmax(fmax(fabs(n0), fabs(n1)), fmax(fabs(n2), fabs(n3)));
  ma = bredd(ma, 1, tmp);
  double s = 127.0 / fmax(ma, 1e-5);
  ((int*)xq)[t * 256 + tid] = qpackd(n0, n1, n2, n3, s);
  if (tid == 0) xsd[t] = s;
}

// act_quant only (rows of 1024 floats), fp64 decisions
__global__ __launch_bounds__(256) void k_actq(const float* X, int8_t* xq, double* xsd) {
  __shared__ double tmp[4];
  int t = blockIdx.x, tid = threadIdx.x;
  float4 xv = ((const float4*)(X + (long long)t * H))[tid];
  double x0 = xv.x, x1 = xv.y, x2 = xv.z, x3 = xv.w;
  double ma = fmax(fmax(fabs(x0), fabs(x1)), fmax(fabs(x2), fabs(x3)));
  ma = bredd(ma, 1, tmp);
  double s = 127.0 / fmax(ma, 1e-5);
  ((int*)xq)[t * 256 + tid] = qpackd(x0, x1, x2, x3, s);
  if (tid == 0) xsd[t] = s;
}

// ---------------- int8 GEMM: out[t,n] = res[t,n] + acc / (xs[t]*sw) ----------------
// k-major LDS tiles: inner loop reads 2x ds_read_b128 per kk (was 8x b32).

__global__ __launch_bounds__(256) void k_gemm(
    const int8_t* __restrict__ Xq, const double* __restrict__ xsd,
    const int8_t* __restrict__ W, const double* __restrict__ wsd, int widx,
    const float* __restrict__ residual, float* __restrict__ out) {
  __shared__ int Xs[32][65];   // [k-int][row], +1 pad: stage-write 2-way, read conflict-free
  __shared__ int Wt[32][65];
  int tid = threadIdx.x;
  int t0 = blockIdx.y * 64, n0 = blockIdx.x * 64;
  const int* Xg = (const int*)Xq;
  const int* Wg = (const int*)W;
  int acc[4][4] = {};
  int lr = tid >> 5, lc = tid & 31;
  int ty = tid >> 4, tx = tid & 15;
  for (int k0 = 0; k0 < 1024; k0 += 128) {
    int kc = k0 >> 2;
#pragma unroll
    for (int i = 0; i < 8; i++) {
      int rr = lr + i * 8;
      Xs[lc][rr] = Xg[(t0 + rr) * 256 + kc + lc];
      Wt[lc][rr] = Wg[(n0 + rr) * 256 + kc + lc];
    }
    __syncthreads();
#pragma unroll
    for (int kk = 0; kk < 32; kk++) {
      int4 a = *(const int4*)&Xs[kk][ty * 4];
      int4 b = *(const int4*)&Wt[kk][tx * 4];
      acc[0][0] = dot4(a.x, b.x, acc[0][0]); acc[0][1] = dot4(a.x, b.y, acc[0][1]);
      acc[0][2] = dot4(a.x, b.z, acc[0][2]); acc[0][3] = dot4(a.x, b.w, acc[0][3]);
      acc[1][0] = dot4(a.y, b.x, acc[1][0]); acc[1][1] = dot4(a.y, b.y, acc[1][1]);
      acc[1][2] = dot4(a.y, b.z, acc[1][2]); acc[1][3] = dot4(a.y, b.w, acc[1][3]);
      acc[2][0] = dot4(a.z, b.x, acc[2][0]); acc[2][1] = dot4(a.z, b.y, acc[2][1]);
      acc[2][2] = dot4(a.z, b.z, acc[2][2]); acc[2][3] = dot4(a.z, b.w, acc[2][3]);
      acc[3][0] = dot4(a.w, b.x, acc[3][0]); acc[3][1] = dot4(a.w, b.y, acc[3][1]);
      acc[3][2] = dot4(a.w, b.z, acc[3][2]); acc[3][3] = dot4(a.w, b.w, acc[3][3]);
    }
    __syncthreads();
  }
  double sw = wsd[widx];
#pragma unroll
  for (int i = 0; i < 4; i++) {
    int t = t0 + ty * 4 + i;
    double inv = 1.0 / (xsd[t] * sw);
#pragma unroll
    for (int j = 0; j < 4; j++) {
      int n = n0 + tx * 4 + j;
      double v = (double)acc[i][j] * inv;
      if (residual) v += (double)residual[(long long)t * H + n];
      out[(long long)t * H + n] = (float)v;
    }
  }
}

// ---------------- attention: flash-tiled, 4-lanes-per-query, Q=2 blocking ----------------
// grid (32 qtiles REVERSED, 16 heads, 2 batch), block 128 = 2 waves, 64 queries/block.
// Wave = 32 queries: quad t serves queries qbase+2t, +2t+1; lane = 4t+dp owns 16 dims.
// Longest-first launch (g = 31-bx) fixes causal load imbalance; Q=2 halves both
// wave-steps and LDS traffic per pair vs R4.

__global__ __launch_bounds__(128) void k_attn(float* __restrict__ QO,
                                              const float* __restrict__ K,
                                              const float* __restrict__ V) {
  __shared__ float Ks[64][68];   // stride 68 keeps 16B alignment; reads 2-way (free)
  __shared__ float Vs[64][68];
  int g = 31 - blockIdx.x;       // reversed: longest blocks dispatch first
  int head = blockIdx.y, b = blockIdx.z;
  int tid = threadIdx.x;
  int wv = tid >> 6, lane = tid & 63;
  int quad = lane >> 2, dp = lane & 3;
  int qlo = g * 64;
  int sqa = qlo + wv * 32 + quad * 2;
  int sqb = sqa + 1;
  int d0 = dp << 4;
  long long rba = ((long long)(b * SEQ + sqa)) * H + head * HD + d0;
  long long rbb = rba + H;

  float4 qa[4], qb[4];
  {
    const float4* pa = (const float4*)(QO + rba);
    const float4* pb = (const float4*)(QO + rbb);
#pragma unroll
    for (int i = 0; i < 4; i++) {
      float4 t = pa[i];
      qa[i] = make_float4(t.x * 0.125f, t.y * 0.125f, t.z * 0.125f, t.w * 0.125f);
      float4 u = pb[i];
      qb[i] = make_float4(u.x * 0.125f, u.y * 0.125f, u.z * 0.125f, u.w * 0.125f);
    }
  }
  float acca[16], accb[16];
#pragma unroll
  for (int i = 0; i < 16; i++) { acca[i] = 0.f; accb[i] = 0.f; }
  float ma = -INFINITY, la = 0.f, mb = -INFINITY, lb = 0.f;

  int nk = qlo + 64;               // keys needed by this block
  int swq = qlo + wv * 32 + 31;    // wave's last query
  int skey = tid >> 1;             // staging: key row 0..63
  int sdc = (tid & 1) << 5;        // staging: d half 0/32

  for (int ko = 0; ko < nk; ko += 64) {
    long long srow = ((long long)(b * SEQ + ko + skey)) * H + head * HD + sdc;
    const float4* kg = (const float4*)(K + srow);
    const float4* vg = (const float4*)(V + srow);
    float4* ksd = (float4*)&Ks[skey][sdc];
    float4* vsd = (float4*)&Vs[skey][sdc];
#pragma unroll
    for (int i = 0; i < 8; i++) ksd[i] = kg[i];
#pragma unroll
    for (int i = 0; i < 8; i++) vsd[i] = vg[i];
    __syncthreads();

    if (ko <= swq) {
      int kmax = (swq - ko + 1 < 64) ? (swq - ko + 1) : 64;
#pragma unroll 2
      for (int kk = 0; kk < kmax; kk++) {
        const float4* kr = (const float4*)&Ks[kk][d0];
        float pa0 = 0.f, pa1 = 0.f, pb0 = 0.f, pb1 = 0.f;
#pragma unroll
        for (int i = 0; i < 4; i++) {
          float4 kv = kr[i];
          pa0 = fmaf(qa[i].x, kv.x, pa0); pa1 = fmaf(qa[i].y, kv.y, pa1);
          pa0 = fmaf(qa[i].z, kv.z, pa0); pa1 = fmaf(qa[i].w, kv.w, pa1);
          pb0 = fmaf(qb[i].x, kv.x, pb0); pb1 = fmaf(qb[i].y, kv.y, pb1);
          pb0 = fmaf(qb[i].z, kv.z, pb0); pb1 = fmaf(qb[i].w, kv.w, pb1);
        }
        float pa = pa0 + pa1, pb = pb0 + pb1;
        pa += __shfl_xor(pa, 1); pa += __shfl_xor(pa, 2);
        pb += __shfl_xor(pb, 1); pb += __shfl_xor(pb, 2);
        int key = ko + kk;
        if (key > sqa) pa = -INFINITY;
        if (key > sqb) pb = -INFINITY;
        bool nma = (pa > ma), nmb = (pb > mb);
        float mna = nma ? pa : ma;
        float mnb = nmb ? pb : mb;
        float wa = __expf(pa - mna);
        float wb = __expf(pb - mnb);
        const float4* vr = (const float4*)&Vs[kk][d0];
        if (__any(nma || nmb)) {
          float ala = __expf(ma - mna);   // ==1 when no new max
          float alb = __expf(mb - mnb);
          la = fmaf(la, ala, wa);
          lb = fmaf(lb, alb, wb);
#pragma unroll
          for (int i = 0; i < 4; i++) {
            float4 vv = vr[i];
            acca[4*i+0] = fmaf(acca[4*i+0], ala, wa * vv.x);
            acca[4*i+1] = fmaf(acca[4*i+1], ala, wa * vv.y);
            acca[4*i+2] = fmaf(acca[4*i+2], ala, wa * vv.z);
            acca[4*i+3] = fmaf(acca[4*i+3], ala, wa * vv.w);
            accb[4*i+0] = fmaf(accb[4*i+0], alb, wb * vv.x);
            accb[4*i+1] = fmaf(accb[4*i+1], alb, wb * vv.y);
            accb[4*i+2] = fmaf(accb[4*i+2], alb, wb * vv.z);
            accb[4*i+3] = fmaf(accb[4*i+3], alb, wb * vv.w);
          }
        } else {
          la += wa; lb += wb;
#pragma unroll
          for (int i = 0; i < 4; i++) {
            float4 vv = vr[i];
            acca[4*i+0] = fmaf(wa, vv.x, acca[4*i+0]);
            acca[4*i+1] = fmaf(wa, vv.y, acca[4*i+1]);
            acca[4*i+2] = fmaf(wa, vv.z, acca[4*i+2]);
            acca[4*i+3] = fmaf(wa, vv.w, acca[4*i+3]);
            accb[4*i+0] = fmaf(wb, vv.x, accb[4*i+0]);
            accb[4*i+1] = fmaf(wb, vv.y, accb[4*i+1]);
            accb[4*i+2] = fmaf(wb, vv.z, accb[4*i+2]);
            accb[4*i+3] = fmaf(wb, vv.w, accb[4*i+3]);
          }
        }
        ma = mna; mb = mnb;
      }
    }
    __syncthreads();
  }

  float ia = 1.f / la, ib = 1.f / lb;
  float4* oa = (float4*)(QO + rba);
  float4* ob = (float4*)(QO + rbb);
#pragma unroll
  for (int i = 0; i < 4; i++) {
    oa[i] = make_float4(acca[4*i] * ia, acca[4*i+1] * ia, acca[4*i+2] * ia, acca[4*i+3] * ia);
    ob[i] = make_float4(accb[4*i] * ib, accb[4*i+1] * ib, accb[4*i+2] * ib, accb[4*i+3] * ib);
  }
}

// ---------------- rmsnorm2 + router (argmax, fp64) + act_quant ----------------

__global__ __launch_bounds__(256) void k_rms2_router(
    const float* X2, const float* lnw, const float* rw,
    int8_t* xq, double* xsd, int* eidx) {
  __shared__ double tmp[4];
  __shared__ double xn[1024];
  __shared__ double logits[8];
  int t = blockIdx.x, tid = threadIdx.x;
  float4 xv = ((const float4*)(X2 + (long long)t * H))[tid];
  double x0 = xv.x, x1 = xv.y, x2 = xv.z, x3 = xv.w;
  double ss = x0 * x0 + x1 * x1 + x2 * x2 + x3 * x3;
  ss = bredd(ss, 0, tmp);
  double r = 1.0 / sqrt(ss * (1.0 / 1024.0) + 1e-5);
  float4 wv = ((const float4*)lnw)[tid];
  double n0 = x0 * r * wv.x, n1 = x1 * r * wv.y, n2 = x2 * r * wv.z, n3 = x3 * r * wv.w;
  xn[tid * 4 + 0] = n0; xn[tid * 4 + 1] = n1;
  xn[tid * 4 + 2] = n2; xn[tid * 4 + 3] = n3;
  double ma = fmax(fmax(fabs(n0), fabs(n1)), fmax(fabs(n2), fabs(n3)));
  ma = bredd(ma, 1, tmp);  // contains syncthreads -> xn visible
  double s = 127.0 / fmax(ma, 1e-5);
  ((int*)xq)[t * 256 + tid] = qpackd(n0, n1, n2, n3, s);
  if (tid == 0) xsd[t] = s;
  if (tid < 64) {
    int e = tid >> 3, i = tid & 7;
    const float* wr = rw + e * 1024;
    double p = 0.0;
    for (int h = i; h < 1024; h += 8) p += xn[h] * (double)wr[h];
    p += __shfl_xor(p, 1);
    p += __shfl_xor(p, 2);
    p += __shfl_xor(p, 4);
    if (i == 0) logits[e] = p;
  }
  __syncthreads();
  if (tid == 0) {
    double best = logits[0];
    int bi = 0;
    for (int e = 1; e < 8; e++)
      if (logits[e] > best) { best = logits[e]; bi = e; }
    eidx[t] = bi;
  }
}

// ---------------- MoE gate/up: hh[t,d] = relu(g)^2 * u for selected expert ----------------

__global__ __launch_bounds__(256) void k_moe_gu(
    const int8_t* __restrict__ xq, const double* __restrict__ xsd,
    const int* __restrict__ eidx, const int8_t* __restrict__ qw,
    const double* __restrict__ wsd, float* __restrict__ hh) {
  __shared__ int xrow[256];
  int t = blockIdx.x, tid = threadIdx.x;
  xrow[tid] = ((const int*)(xq + (long long)t * H))[tid];
  __syncthreads();
  int e = eidx[t];
  double st = xsd[t];
  double inv_g = 1.0 / (st * wsd[4 + e]);
  double inv_u = 1.0 / (st * wsd[12 + e]);
  const int* gbase = (const int*)qw + ((long long)(4 + e) << 18);
  const int* ubase = (const int*)qw + ((long long)(12 + e) << 18);
  int wid = tid >> 6, lane = tid & 63;
  for (int d = wid; d < DDIM; d += 4) {
    const int* gr = gbase + d * 256;
    const int* ur = ubase + d * 256;
    int ag = 0, au = 0;
#pragma unroll
    for (int c = 0; c < 4; c++) {
      int xc = xrow[lane + c * 64];
      ag = dot4(gr[lane + c * 64], xc, ag);
      au = dot4(ur[lane + c * 64], xc, au);
    }
#pragma unroll
    for (int o = 32; o; o >>= 1) {
      ag += __shfl_xor(ag, o);
      au += __shfl_xor(au, o);
    }
    if (lane == 0) {
      double g = (double)ag * inv_g, u = (double)au * inv_u;
      double rg = fmax(g, 0.0);
      hh[(long long)t * DDIM + d] = (float)(rg * rg * u);
    }
  }
}

// ---------------- MoE down + residual -> final output ----------------

__global__ __launch_bounds__(256) void k_moe_down(
    const int8_t* __restrict__ hq, const double* __restrict__ hsd,
    const int* __restrict__ eidx, const int8_t* __restrict__ qw,
    const double* __restrict__ wsd, const float* __restrict__ x2,
    float* __restrict__ out) {
  __shared__ int xrow[256];
  int t = blockIdx.x, tid = threadIdx.x;
  xrow[tid] = ((const int*)(hq + (long long)t * DDIM))[tid];
  __syncthreads();
  int e = eidx[t];
  double inv = 1.0 / (hsd[t] * wsd[20 + e]);
  const int* dbase = (const int*)qw + ((long long)(20 + e) << 18);
  int wid = tid >> 6, lane = tid & 63;
  for (int h = wid; h < H; h += 4) {
    const int* dr = dbase + h * 256;
    int a = 0;
#pragma unroll
    for (int c = 0; c < 4; c++) a = dot4(dr[lane + c * 64], xrow[lane + c * 64], a);
#pragma unroll
    for (int o = 32; o; o >>= 1) a += __shfl_xor(a, o);
    if (lane == 0)
      out[(long long)t * H + h] = (float)((double)x2[(long long)t * H + h] + (double)a * inv);
  }
}

// ---------------- launch ----------------
// ws layout (bytes):
//   0        partial double[28*1024]  (224 KB)
//   229376   wsd double[28]
//   229600   xsd double[4096] (32 KB)
//   262368   eidx int[4096]
//   1MB      qw int8: 28 x 1MB (q,k,v,o, gate[8], up[8], down[8])
//   32MB     qbuf fp32 16MB (q -> attn out in place)
//   48MB     kbuf fp32 16MB (k -> moe hh)
//   64MB     vbuf fp32 16MB (v -> x2 residual)
//   80MB     xq int8 4MB  (act_quant buffer, reused 4x)

extern "C" void kernel_launch(void* const* d_in, const int* in_sizes, int n_in,
                              void* d_out, int out_size, void* d_ws, size_t ws_size,
                              hipStream_t stream) {
  const float* x   = (const float*)d_in[0];
  const float* qw_ = (const float*)d_in[1];
  const float* kw_ = (const float*)d_in[2];
  const float* vw_ = (const float*)d_in[3];
  const float* ow_ = (const float*)d_in[4];
  const float* ln1 = (const float*)d_in[5];
  const float* ln2 = (const float*)d_in[6];
  const float* rw  = (const float*)d_in[7];
  const float* gw  = (const float*)d_in[8];
  const float* uw  = (const float*)d_in[9];
  const float* dw  = (const float*)d_in[10];
  float* out = (float*)d_out;

  uint8_t* ws = (uint8_t*)d_ws;
  double* partial = (double*)ws;
  double* wsd   = (double*)(ws + 229376);
  double* xsd   = (double*)(ws + 229600);
  int*    eidx  = (int*)(ws + 262368);
  int8_t* qw    = (int8_t*)(ws + (1ull << 20));
  float*  qbuf  = (float*)(ws + (32ull << 20));
  float*  kbuf  = (float*)(ws + (48ull << 20));
  float*  vbuf  = (float*)(ws + (64ull << 20));
  int8_t* xq    = (int8_t*)(ws + (80ull << 20));

  // weight quantization (deterministic fp64 scales)
  k_absum<<<28 * 1024, 256, 0, stream>>>(qw_, kw_, vw_, ow_, gw, uw, dw, partial);
  k_wscale<<<28, 256, 0, stream>>>(partial, wsd);
  k_quantw<<<28 * 1024, 256, 0, stream>>>(qw_, kw_, vw_, ow_, gw, uw, dw, wsd, qw);

  // attention input: rmsnorm + act_quant
  k_rms1<<<NTOK, 256, 0, stream>>>(x, ln1, xq, xsd);
  // q/k/v projections (exact int8 x ternary GEMM)
  k_gemm<<<dim3(16, 64), 256, 0, stream>>>(xq, xsd, qw,             wsd, 0, nullptr, qbuf);
  k_gemm<<<dim3(16, 64), 256, 0, stream>>>(xq, xsd, qw + (1 << 20), wsd, 1, nullptr, kbuf);
  k_gemm<<<dim3(16, 64), 256, 0, stream>>>(xq, xsd, qw + (2 << 20), wsd, 2, nullptr, vbuf);
  // causal flash attention, h written in place over qbuf
  k_attn<<<dim3(32, NHEAD, 2), 128, 0, stream>>>(qbuf, kbuf, vbuf);
  // o projection with residual: x2 = x + bitlinear(h, o_w) -> vbuf
  k_actq<<<NTOK, 256, 0, stream>>>(qbuf, xq, xsd);
  k_gemm<<<dim3(16, 64), 256, 0, stream>>>(xq, xsd, qw + (3 << 20), wsd, 3, x, vbuf);
  // MoE: rmsnorm2 + router argmax + act_quant
  k_rms2_router<<<NTOK, 256, 0, stream>>>(vbuf, ln2, rw, xq, xsd, eidx);
  k_moe_gu<<<NTOK, 256, 0, stream>>>(xq, xsd, eidx, qw, wsd, kbuf);
  k_actq<<<NTOK, 256, 0, stream>>>(kbuf, xq, xsd);
  k_moe_down<<<NTOK, 256, 0, stream>>>(xq, xsd, eidx, qw, wsd, vbuf, out);
}